// Round 15
// baseline (186.132 us; speedup 1.0000x reference)
//
#include <hip/hip_runtime.h>
#include <math.h>

#define Bn 32
#define Cn 64
#define Ln 2048
#define NFREQ 1025
#define S0c 341
#define S1c 341
#define S2c 343
#define KPAD 352              // per-band padded K (multiple of 32, >= max band size)
#define XROW (3 * 1056)       // XS row stride in u16: 3 planes x (3 bands x 352)
#define APLANE (3 * KPAD * KPAD)  // AS plane stride in u16

#define PI_D 3.14159265358979323846

typedef double v4d __attribute__((ext_vector_type(4)));
typedef unsigned short u16;
typedef __attribute__((ext_vector_type(4))) u16 u16x4;
typedef __attribute__((ext_vector_type(8))) short short8;
typedef __attribute__((ext_vector_type(4))) float f32x4;

// padded LDS index: breaks power-of-2 stride bank conflicts
#define PADIX(i) ((i) + ((i) >> 4))

// round-to-nearest-even f32 -> bf16 (bit trick, exact RNE incl. mantissa carry)
__device__ __forceinline__ u16 rneb(float f) {
    unsigned u = __float_as_uint(f);
    unsigned r = (u + 0x7FFFu + ((u >> 16) & 1u)) >> 16;
    return (u16)r;
}
__device__ __forceinline__ float b2f(u16 h) {
    return __uint_as_float(((unsigned)h) << 16);
}
// exact 3-way split: v == b2f(h1)+b2f(h2)+b2f(h3) + O(2^-24 ulp)
__device__ __forceinline__ void split3(float v, u16& h1, u16& h2, u16& h3) {
    h1 = rneb(v);
    float r1 = v - b2f(h1);     // exact (Sterbenz)
    h2 = rneb(r1);
    float r2 = r1 - b2f(h2);    // exact
    h3 = rneb(r2);
}

// radix-4 digit reversal of a 10-bit index
__device__ __forceinline__ int rev4_10(unsigned x) {
    unsigned t = __brev(x) >> 22;                       // full 10-bit reversal
    return (int)(((t & 0x155u) << 1) | ((t >> 1) & 0x155u));  // un-reverse bit pairs
}

// ---------------- K1: fused rfft + A-pre-split + counter zero (one dispatch) ----------------
// blocks 0..2047: f32 rfft of one row (per-block LDS twiddles, proven r14).
// blocks 2048..3499: split A0/A1/A2 into 3 zero-padded 352x352 bf16 planes.
// first A-block also zeroes the 32 per-batch dist counters (stream-ordered before k_dist).
__global__ __launch_bounds__(256) void k_fftprep(const float* __restrict__ X,
                                                 const float* __restrict__ A0,
                                                 const float* __restrict__ A1,
                                                 const float* __restrict__ A2,
                                                 u16* __restrict__ XS,
                                                 u16* __restrict__ AS,
                                                 unsigned* __restrict__ cnt) {
    __shared__ float re[1088];
    __shared__ float im[1088];
    __shared__ float2 twl[2048];
    int blk = blockIdx.x;
    int tid = threadIdx.x;

    if (blk >= Bn * Cn) {
        // ---- A pre-split path ----
        int i = blk - Bn * Cn;         // 0..1451 ; 484 blocks per band (484*256 == 352*352)
        if (i == 0 && tid < Bn) cnt[tid] = 0;   // zero last-block-done counters
        int z = i / 484;
        const float* A = (z == 0) ? A0 : ((z == 1) ? A1 : A2);
        int S = (z == 2) ? S2c : S0c;
        int idx = (i % 484) * 256 + tid;
        int d = idx / KPAD, kk = idx - d * KPAD;
        float v = (d < S && kk < S) ? A[(size_t)d * S + kk] : 0.0f;
        u16 h1, h2, h3;
        split3(v, h1, h2, h3);
        size_t o = ((size_t)z * KPAD + d) * KPAD + kk;
        AS[o] = h1;
        AS[APLANE + o] = h2;
        AS[2 * (size_t)APLANE + o] = h3;
        return;
    }

    // ---- FFT path ----
    int row = blk;
    #pragma unroll
    for (int ii = 0; ii < 8; ++ii) {
        int t = tid + 256 * ii;
        float ang = (float)(-2.0 * PI_D / 2048.0 * (double)t);
        float s, c;
        sincosf(ang, &s, &c);
        twl[t] = make_float2(c, s);
    }
    __syncthreads();
    // ---- stage 0 (Q=256) in registers from global loads ----
    {
        int k = tid;
        float2 w1 = twl[2 * k];
        float2 w2 = twl[4 * k];
        float2 w3 = twl[6 * k];
        int i0 = PADIX(k), i1 = PADIX(k + 256), i2 = PADIX(k + 512), i3 = PADIX(k + 768);
        const float2* xr = (const float2*)(X + (size_t)row * Ln);
        float2 v0 = xr[k];
        float2 v1 = xr[k + 256];
        float2 v2 = xr[k + 512];
        float2 v3 = xr[k + 768];
        float ar = v0.x, ai = v0.y;
        float br = v1.x, bi = v1.y;
        float cr = v2.x, ci = v2.y;
        float dr = v3.x, di = v3.y;
        float t0r = ar + cr, t0i = ai + ci;
        float t1r = ar - cr, t1i = ai - ci;
        float t2r = br + dr, t2i = bi + di;
        float t3r = br - dr, t3i = bi - di;
        re[i0] = t0r + t2r; im[i0] = t0i + t2i;
        float u1r = t1r + t3i, u1i = t1i - t3r;
        re[i1] = u1r * w1.x - u1i * w1.y; im[i1] = u1r * w1.y + u1i * w1.x;
        float u2r = t0r - t2r, u2i = t0i - t2i;
        re[i2] = u2r * w2.x - u2i * w2.y; im[i2] = u2r * w2.y + u2i * w2.x;
        float u3r = t1r - t3i, u3i = t1i + t3r;
        re[i3] = u3r * w3.x - u3i * w3.y; im[i3] = u3r * w3.y + u3i * w3.x;
    }
    __syncthreads();
    // ---- stages 1..4 through LDS ----
    #pragma unroll
    for (int s = 1; s < 5; ++s) {
        int log2Q = 8 - 2 * s;
        int Q = 1 << log2Q;
        int k = tid & (Q - 1);
        int g = tid >> log2Q;
        int base = (g << (log2Q + 2)) + k;
        int i0 = PADIX(base), i1 = PADIX(base + Q), i2 = PADIX(base + 2 * Q), i3 = PADIX(base + 3 * Q);
        int step = 2 << (2 * s);
        float2 w1 = twl[k * step];
        float2 w2 = twl[2 * k * step];
        float2 w3 = twl[3 * k * step];
        float ar = re[i0], ai = im[i0];
        float br = re[i1], bi = im[i1];
        float cr = re[i2], ci = im[i2];
        float dr = re[i3], di = im[i3];
        float t0r = ar + cr, t0i = ai + ci;
        float t1r = ar - cr, t1i = ai - ci;
        float t2r = br + dr, t2i = bi + di;
        float t3r = br - dr, t3i = bi - di;
        re[i0] = t0r + t2r; im[i0] = t0i + t2i;
        float u1r = t1r + t3i, u1i = t1i - t3r;
        re[i1] = u1r * w1.x - u1i * w1.y; im[i1] = u1r * w1.y + u1i * w1.x;
        float u2r = t0r - t2r, u2i = t0i - t2i;
        re[i2] = u2r * w2.x - u2i * w2.y; im[i2] = u2r * w2.y + u2i * w2.x;
        float u3r = t1r - t3i, u3i = t1i + t3r;
        re[i3] = u3r * w3.x - u3i * w3.y; im[i3] = u3r * w3.y + u3i * w3.x;
        __syncthreads();
    }
    // split: X[k] = E_k + e^{-2pi i k/2048} O_k (Z positions radix-4-digit-reversed)
    u16* xrow = XS + (size_t)row * XROW;
    if (tid < 31) {   // zero the band pad cells (341..351 | 693..703 | 1047..1055)
        int pp = (tid < 11) ? (341 + tid) : ((tid < 22) ? (682 + tid) : (1025 + tid));
        xrow[pp] = 0; xrow[1056 + pp] = 0; xrow[2112 + pp] = 0;
    }
    for (int k = tid; k <= 1024; k += 256) {
        float Xr, Xi;
        if (k == 0)        { Xr = re[0] + im[0]; Xi = 0.0f; }
        else if (k == 1024){ Xr = re[0] - im[0]; Xi = 0.0f; }
        else {
            int rv  = PADIX(rev4_10((unsigned)k));
            int rv2 = PADIX(rev4_10((unsigned)(1024 - k)));
            float2 t = twl[k];
            float Zr = re[rv],  Zi = im[rv];
            float Wr = re[rv2], Wi = im[rv2];
            float Er = 0.5f * (Zr + Wr), Ei = 0.5f * (Zi - Wi);
            float Or = 0.5f * (Zi + Wi), Oi = -0.5f * (Zr - Wr);
            Xr = Er + t.x * Or - t.y * Oi;
            Xi = Ei + t.x * Oi + t.y * Or;
        }
        float v = sqrtf(Xr * Xr + Xi * Xi);
        int zb = (k < S0c) ? 0 : ((k < S0c + S1c) ? 1 : 2);
        int pos = k + 11 * zb;   // z*352 + (k - O): band offsets 0/341/682 -> +0/+11/+22
        u16 h1, h2, h3;
        split3(v, h1, h2, h3);
        xrow[pos] = h1;
        xrow[1056 + pos] = h2;
        xrow[2112 + pos] = h3;
    }
}

// ---------------- K3: fused 3-band GEMM via pre-split bf16 planes ----------------
// r8 geometry (proven): wave tile 32x16, block 64x32, grid (32,11,3)=1056 (~4.1/CU).
// Y stored f32 (f64 accumulate, cast at store). Session ladder: 162.5 -> 134.0.
// Negative results, do not retry: r1/r2 ILP-via-VGPR (-23%), r5 LDS dbuf (neutral),
// r11 dist-fusion with in-loop split (+2), r12 epilogue-scatter + 32-block dist (+10).
__global__ __launch_bounds__(256) void k_gemm(const u16* __restrict__ XS,
                                              const u16* __restrict__ AS,
                                              float* __restrict__ Y) {
    const int Sarr[3] = {S0c, S1c, S2c};
    const int Oarr[3] = {0, S0c, S0c + S1c};
    int z = blockIdx.z;
    int S = Sarr[z], O = Oarr[z];

    __shared__ u16 sX1[64][40], sX2[64][40], sX3[64][40];   // X rows (stride 40: b128-aligned)
    __shared__ u16 sA1[32][40], sA2[32][40], sA3[32][40];   // A cols(d)

    int r0 = blockIdx.x * 64;
    int d0 = blockIdx.y * 32;
    int tid = threadIdx.x;
    int lane = tid & 63, w = tid >> 6;
    int wm = (w >> 1) * 32, wn = (w & 1) * 16;   // wave tile: rows [wm,wm+32), cols [wn,wn+16)
    int fm = lane & 15, kq = lane >> 4;
    int row8 = tid >> 3, seg4 = (tid & 7) * 4;   // staging: 1 row x 4 contiguous k / thread

    // ---- runtime C/D layout calibration via the bf16 MFMA itself ----
    f32x4 z4 = {0.0f, 0.0f, 0.0f, 0.0f};
    short8 aone, afm;
    {
        u16 hone = 0x3F80;                 // bf16(1.0)
        u16 hfm = rneb((float)fm);         // exact for 0..15
        #pragma unroll
        for (int j = 0; j < 8; ++j) { aone[j] = (short)hone; afm[j] = (short)hfm; }
    }
    f32x4 calR = __builtin_amdgcn_mfma_f32_16x16x32_bf16(afm, aone, z4, 0, 0, 0);  // 32*row
    f32x4 calC = __builtin_amdgcn_mfma_f32_16x16x32_bf16(aone, afm, z4, 0, 0, 0);  // 32*col
    int rIdx[4], cIdx[4];
    #pragma unroll
    for (int i = 0; i < 4; ++i) {
        rIdx[i] = (int)(calR[i] * 0.03125f + 0.5f);
        cIdx[i] = (int)(calC[i] * 0.03125f + 0.5f);
    }

    // staging sources: X rows row8 and row8+32; A col-row row8 (all u16x4 8B-aligned)
    const u16* xb0 = XS + (size_t)(r0 + row8) * XROW + (size_t)z * KPAD + seg4;
    const u16* xb1 = xb0 + 32 * (size_t)XROW;
    const u16* ab  = AS + ((size_t)z * KPAD + (d0 + row8)) * KPAD + seg4;

    u16x4 wxa1, wxa2, wxa3, wxb1, wxb2, wxb3, wa1, wa2, wa3;
    auto load_tile = [&](int st) {
        int ko = st * 32;
        wxa1 = *(const u16x4*)(xb0 + ko);
        wxa2 = *(const u16x4*)(xb0 + 1056 + ko);
        wxa3 = *(const u16x4*)(xb0 + 2112 + ko);
        wxb1 = *(const u16x4*)(xb1 + ko);
        wxb2 = *(const u16x4*)(xb1 + 1056 + ko);
        wxb3 = *(const u16x4*)(xb1 + 2112 + ko);
        wa1  = *(const u16x4*)(ab + ko);
        wa2  = *(const u16x4*)(ab + APLANE + ko);
        wa3  = *(const u16x4*)(ab + 2 * (size_t)APLANE + ko);
    };

    double acc0[4] = {0.0, 0.0, 0.0, 0.0};
    double acc1[4] = {0.0, 0.0, 0.0, 0.0};
    load_tile(0);
    const int nsteps = KPAD / 32;   // 11, uniform across bands
    for (int st = 0; st < nsteps; ++st) {
        __syncthreads();
        *(u16x4*)&sX1[row8][seg4] = wxa1;
        *(u16x4*)&sX2[row8][seg4] = wxa2;
        *(u16x4*)&sX3[row8][seg4] = wxa3;
        *(u16x4*)&sX1[row8 + 32][seg4] = wxb1;
        *(u16x4*)&sX2[row8 + 32][seg4] = wxb2;
        *(u16x4*)&sX3[row8 + 32][seg4] = wxb3;
        *(u16x4*)&sA1[row8][seg4] = wa1;
        *(u16x4*)&sA2[row8][seg4] = wa2;
        *(u16x4*)&sA3[row8][seg4] = wa3;
        __syncthreads();
        if (st + 1 < nsteps) load_tile(st + 1);
        short8 b1 = *(const short8*)&sA1[wn + fm][kq * 8];
        short8 b2 = *(const short8*)&sA2[wn + fm][kq * 8];
        short8 b3 = *(const short8*)&sA3[wn + fm][kq * 8];
        {   // row-subtile 0: rows wm..wm+15
            short8 a1 = *(const short8*)&sX1[wm + fm][kq * 8];
            short8 a2 = *(const short8*)&sX2[wm + fm][kq * 8];
            short8 a3 = *(const short8*)&sX3[wm + fm][kq * 8];
            f32x4 p1 = __builtin_amdgcn_mfma_f32_16x16x32_bf16(a1, b1, z4, 0, 0, 0);
            f32x4 p2 = __builtin_amdgcn_mfma_f32_16x16x32_bf16(a1, b2, z4, 0, 0, 0);
            p2 = __builtin_amdgcn_mfma_f32_16x16x32_bf16(a2, b1, p2, 0, 0, 0);
            p2 = __builtin_amdgcn_mfma_f32_16x16x32_bf16(a1, b3, p2, 0, 0, 0);
            p2 = __builtin_amdgcn_mfma_f32_16x16x32_bf16(a2, b2, p2, 0, 0, 0);
            p2 = __builtin_amdgcn_mfma_f32_16x16x32_bf16(a3, b1, p2, 0, 0, 0);
            #pragma unroll
            for (int i = 0; i < 4; ++i) acc0[i] += (double)p1[i] + (double)p2[i];
        }
        {   // row-subtile 1: rows wm+16..wm+31
            short8 a1 = *(const short8*)&sX1[wm + 16 + fm][kq * 8];
            short8 a2 = *(const short8*)&sX2[wm + 16 + fm][kq * 8];
            short8 a3 = *(const short8*)&sX3[wm + 16 + fm][kq * 8];
            f32x4 p1 = __builtin_amdgcn_mfma_f32_16x16x32_bf16(a1, b1, z4, 0, 0, 0);
            f32x4 p2 = __builtin_amdgcn_mfma_f32_16x16x32_bf16(a1, b2, z4, 0, 0, 0);
            p2 = __builtin_amdgcn_mfma_f32_16x16x32_bf16(a2, b1, p2, 0, 0, 0);
            p2 = __builtin_amdgcn_mfma_f32_16x16x32_bf16(a1, b3, p2, 0, 0, 0);
            p2 = __builtin_amdgcn_mfma_f32_16x16x32_bf16(a2, b2, p2, 0, 0, 0);
            p2 = __builtin_amdgcn_mfma_f32_16x16x32_bf16(a3, b1, p2, 0, 0, 0);
            #pragma unroll
            for (int i = 0; i < 4; ++i) acc1[i] += (double)p1[i] + (double)p2[i];
        }
    }
    #pragma unroll
    for (int i = 0; i < 4; ++i) {
        int d = d0 + wn + cIdx[i];
        if (d < S) {
            Y[(size_t)(r0 + wm + rIdx[i]) * NFREQ + O + d] = (float)acc0[i];
            Y[(size_t)(r0 + wm + 16 + rIdx[i]) * NFREQ + O + d] = (float)acc1[i];
        }
    }
}

// ---------------- K4: Gram partials + last-block-done gumbel decision (round-15) ----------------
// grid (32 batches, 8 dim-chunks) = 256 blocks (proven r10 geometry). Each block writes its
// f64 Gram partial, then device-release (__threadfence) + atomicAdd on cnt[b]; the 8th
// arrival acquires and runs the full decide for its batch in-block (exact r13 k_decide body,
// looped over 16 row-groups). Kills k_decide's launch + dispatch gap; no grid starvation
// (dist stays 256 blocks; decide epilogue overlaps other batches' dist blocks).
__global__ __launch_bounds__(256) void k_dist(const float* __restrict__ Y,
                                              const float* __restrict__ fw,
                                              double* __restrict__ part,
                                              unsigned* __restrict__ cnt,
                                              const float* __restrict__ gum,
                                              float* __restrict__ out) {
    __shared__ double sY[64][34];   // [row][k] f64
    __shared__ int isLast;
    int b = blockIdx.x;
    int chunk = blockIdx.y;
    int dlo = chunk * 128;
    int dhi = (chunk == 7) ? NFREQ : dlo + 128;
    int tid = threadIdx.x;
    int lane = tid & 63, w = tid >> 6;
    int wm = (w >> 1) * 32, wn = (w & 1) * 32;
    int fm = lane & 15, kq = lane >> 4;
    int kl = tid & 31, rl = tid >> 5;

    double f0 = (double)fw[0], f1 = (double)fw[1], f2 = (double)fw[2];
    double m = fmax(f0, fmax(f1, f2));
    double e0 = exp(f0 - m), e1 = exp(f1 - m), e2 = exp(f2 - m);
    double esum = e0 + e1 + e2;
    double sw0 = sqrt(e0 / esum), sw1 = sqrt(e1 / esum), sw2 = sqrt(e2 / esum);

    v4d zero = {0.0, 0.0, 0.0, 0.0};
    double aval = (double)fm;
    v4d calR = __builtin_amdgcn_mfma_f64_16x16x4f64(aval, 1.0, zero, 0, 0, 0);
    v4d calC = __builtin_amdgcn_mfma_f64_16x16x4f64(1.0, aval, zero, 0, 0, 0);
    int rIdx[4], cIdx[4];
    #pragma unroll
    for (int i = 0; i < 4; ++i) {
        rIdx[i] = (int)(calR[i] * 0.25);
        cIdx[i] = (int)(calC[i] * 0.25);
    }

    const float* Yb = Y + (size_t)b * Cn * NFREQ;
    auto load_tile = [&](int k0, double* py) {
        int d = dlo + k0 + kl;
        bool dv = d < dhi;
        double sw = dv ? ((d < S0c) ? sw0 : ((d < S0c + S1c) ? sw1 : sw2)) : 0.0;
        #pragma unroll
        for (int i = 0; i < 8; ++i)
            py[i] = dv ? (double)Yb[(size_t)(rl + 8 * i) * NFREQ + d] * sw : 0.0;
    };

    v4d acc00 = zero, acc01 = zero, acc10 = zero, acc11 = zero;
    double py[8];
    load_tile(0, py);
    int nsteps = (dhi - dlo + 31) / 32;
    for (int st = 0; st < nsteps; ++st) {
        __syncthreads();
        #pragma unroll
        for (int i = 0; i < 8; ++i) sY[rl + 8 * i][kl] = py[i];
        __syncthreads();
        if (st + 1 < nsteps) load_tile((st + 1) * 32, py);
        #pragma unroll
        for (int t = 0; t < 8; ++t) {
            int k = 4 * t + kq;
            double a0 = sY[wm + fm][k];
            double a1 = sY[wm + 16 + fm][k];
            double b0 = sY[wn + fm][k];
            double b1 = sY[wn + 16 + fm][k];
            acc00 = __builtin_amdgcn_mfma_f64_16x16x4f64(a0, b0, acc00, 0, 0, 0);
            acc01 = __builtin_amdgcn_mfma_f64_16x16x4f64(a0, b1, acc01, 0, 0, 0);
            acc10 = __builtin_amdgcn_mfma_f64_16x16x4f64(a1, b0, acc10, 0, 0, 0);
            acc11 = __builtin_amdgcn_mfma_f64_16x16x4f64(a1, b1, acc11, 0, 0, 0);
        }
    }
    double* pb0 = part + (((size_t)b * 8) << 12);
    double* pb = pb0 + ((size_t)chunk << 12);
    #pragma unroll
    for (int i = 0; i < 4; ++i) {
        int rowA = wm + rIdx[i], rowB = rowA + 16;
        int cA = wn + cIdx[i], cB = cA + 16;
        pb[rowA * 64 + cA] = acc00[i];
        pb[rowA * 64 + cB] = acc01[i];
        pb[rowB * 64 + cA] = acc10[i];
        pb[rowB * 64 + cB] = acc11[i];
    }

    // ---- last-block-done handoff (threadFenceReduction pattern) ----
    __threadfence();            // release: partial visible device-wide (cross-XCD)
    __syncthreads();
    if (tid == 0) isLast = (atomicAdd(&cnt[b], 1u) == 7u);
    __syncthreads();
    if (!isLast) return;
    __threadfence();            // acquire: see all 8 chunks' partials

    // ---- decide for batch b (exact r13 k_decide body, 16 row-group passes) ----
    __shared__ double sQ[64];
    if (tid < 64) {
        double q = 0.0;
        #pragma unroll
        for (int c = 0; c < 8; ++c) q += pb0[((size_t)c << 12) + tid * 65];
        sQ[tid] = q;
    }
    __syncthreads();
    const float* gb = gum + (size_t)b * 8192;
    float* ob = out + (size_t)b * 4096;
    for (int pass = 0; pass < 16; ++pass) {
        int i = pass * 4 + (tid >> 6);
        int j = tid & 63;
        double g = 0.0;
        #pragma unroll
        for (int c = 0; c < 8; ++c) g += pb0[((size_t)c << 12) + i * 64 + j];
        double dist = fmax(sQ[i] + sQ[j] - 2.0 * g, 0.0);
        double e = (i == j) ? 0.0 : 1.0 / (dist + 1e-10);
        double emax = e;
        #pragma unroll
        for (int off = 32; off; off >>= 1)
            emax = fmax(emax, __shfl_xor(emax, off, 64));
        double p = (i == j) ? 0.99 : (e / emax) * 0.99;
        double l0 = log(p / (1.0 - p));
        int idx = i * 64 + j;
        double y0 = l0 + (double)gb[2 * idx];
        double y1 = -l0 + (double)gb[2 * idx + 1];
        ob[idx] = (y0 >= y1) ? 1.0f : 0.0f;   // ST == one-hot exactly
    }
}

// ---------------- launcher ----------------
extern "C" void kernel_launch(void* const* d_in, const int* in_sizes, int n_in,
                              void* d_out, int out_size, void* d_ws, size_t ws_size,
                              hipStream_t stream) {
    const float* X  = (const float*)d_in[0];
    const float* A0 = (const float*)d_in[1];
    const float* A1 = (const float*)d_in[2];
    const float* A2 = (const float*)d_in[3];
    const float* fw = (const float*)d_in[4];
    const float* gm = (const float*)d_in[5];
    float* out = (float*)d_out;

    char* ws = (char*)d_ws;
    unsigned* cnt = (unsigned*)(ws);               // 32 x 4 B (zeroed by k_fftprep)
    u16*  XS = (u16*)(ws + 32768);                 // 2048*3168*2 = 12,976,128 B -> ends 13,008,896
    u16*  AS = (u16*)(ws + 13008896);              // 3*371712*2  =  2,230,272 B -> ends 15,239,168
    float* Y = (float*)(ws + 15239168);            // 2048*1025*4 = 8,396,800 B -> ends 23,635,968
    // part aliases XS (dead after gemm): 32*8*4096*8 = 8,388,608 B <= 12,976,128 B
    double* part = (double*)(ws + 32768);

    k_fftprep<<<Bn * Cn + 1452, 256, 0, stream>>>(X, A0, A1, A2, XS, AS, cnt);
    k_gemm<<<dim3(32, 11, 3), 256, 0, stream>>>(XS, AS, Y);
    k_dist<<<dim3(Bn, 8), 256, 0, stream>>>(Y, fw, part, cnt, gm, out);
}

// Round 16
// 134.577 us; speedup vs baseline: 1.3831x; 1.3831x over previous
//
#include <hip/hip_runtime.h>
#include <math.h>

#define Bn 32
#define Cn 64
#define Ln 2048
#define NFREQ 1025
#define S0c 341
#define S1c 341
#define S2c 343
#define KPAD 352              // per-band padded K (multiple of 32, >= max band size)
#define XROW (3 * 1056)       // XS row stride in u16: 3 planes x (3 bands x 352)
#define APLANE (3 * KPAD * KPAD)  // AS plane stride in u16

#define PI_D 3.14159265358979323846

typedef double v4d __attribute__((ext_vector_type(4)));
typedef unsigned short u16;
typedef __attribute__((ext_vector_type(4))) u16 u16x4;
typedef __attribute__((ext_vector_type(8))) short short8;
typedef __attribute__((ext_vector_type(4))) float f32x4;

// padded LDS index: breaks power-of-2 stride bank conflicts
#define PADIX(i) ((i) + ((i) >> 4))

// round-to-nearest-even f32 -> bf16 (bit trick, exact RNE incl. mantissa carry)
__device__ __forceinline__ u16 rneb(float f) {
    unsigned u = __float_as_uint(f);
    unsigned r = (u + 0x7FFFu + ((u >> 16) & 1u)) >> 16;
    return (u16)r;
}
__device__ __forceinline__ float b2f(u16 h) {
    return __uint_as_float(((unsigned)h) << 16);
}
// exact 3-way split: v == b2f(h1)+b2f(h2)+b2f(h3) + O(2^-24 ulp)
__device__ __forceinline__ void split3(float v, u16& h1, u16& h2, u16& h3) {
    h1 = rneb(v);
    float r1 = v - b2f(h1);     // exact (Sterbenz)
    h2 = rneb(r1);
    float r2 = r1 - b2f(h2);    // exact
    h3 = rneb(r2);
}

// radix-4 digit reversal of a 10-bit index
__device__ __forceinline__ int rev4_10(unsigned x) {
    unsigned t = __brev(x) >> 22;                       // full 10-bit reversal
    return (int)(((t & 0x155u) << 1) | ((t >> 1) & 0x155u));  // un-reverse bit pairs
}

// ---------------- K1: fused rfft + A-pre-split (one dispatch; r14, session best) ----------------
// blocks 0..2047: f32 rfft of one row, per-block LDS twiddles.
// blocks 2048..3499: split A0/A1/A2 into 3 zero-padded 352x352 bf16 planes.
// NOTE r15 negative result: fusing decide into dist via last-block-done + device
// __threadfence per block cost +52 us (cross-XCD coherence stalls; k_dist 10 -> 80 us).
// Kernel-boundary handoff is CHEAPER than intra-dispatch producer-consumer on 8-XCD CDNA4.
__global__ __launch_bounds__(256) void k_fftprep(const float* __restrict__ X,
                                                 const float* __restrict__ A0,
                                                 const float* __restrict__ A1,
                                                 const float* __restrict__ A2,
                                                 u16* __restrict__ XS,
                                                 u16* __restrict__ AS) {
    __shared__ float re[1088];
    __shared__ float im[1088];
    __shared__ float2 twl[2048];
    int blk = blockIdx.x;
    int tid = threadIdx.x;

    if (blk >= Bn * Cn) {
        // ---- A pre-split path ----
        int i = blk - Bn * Cn;         // 0..1451 ; 484 blocks per band (484*256 == 352*352)
        int z = i / 484;
        const float* A = (z == 0) ? A0 : ((z == 1) ? A1 : A2);
        int S = (z == 2) ? S2c : S0c;
        int idx = (i % 484) * 256 + tid;
        int d = idx / KPAD, kk = idx - d * KPAD;
        float v = (d < S && kk < S) ? A[(size_t)d * S + kk] : 0.0f;
        u16 h1, h2, h3;
        split3(v, h1, h2, h3);
        size_t o = ((size_t)z * KPAD + d) * KPAD + kk;
        AS[o] = h1;
        AS[APLANE + o] = h2;
        AS[2 * (size_t)APLANE + o] = h3;
        return;
    }

    // ---- FFT path ----
    int row = blk;
    // per-block twiddle table: tw[t] = e^{-2 pi i t / 2048}; angle in f64, rounded to f32
    #pragma unroll
    for (int ii = 0; ii < 8; ++ii) {
        int t = tid + 256 * ii;
        float ang = (float)(-2.0 * PI_D / 2048.0 * (double)t);
        float s, c;
        sincosf(ang, &s, &c);
        twl[t] = make_float2(c, s);
    }
    __syncthreads();
    // ---- stage 0 (Q=256) in registers from global loads ----
    {
        int k = tid;
        float2 w1 = twl[2 * k];
        float2 w2 = twl[4 * k];
        float2 w3 = twl[6 * k];
        int i0 = PADIX(k), i1 = PADIX(k + 256), i2 = PADIX(k + 512), i3 = PADIX(k + 768);
        const float2* xr = (const float2*)(X + (size_t)row * Ln);
        float2 v0 = xr[k];
        float2 v1 = xr[k + 256];
        float2 v2 = xr[k + 512];
        float2 v3 = xr[k + 768];
        float ar = v0.x, ai = v0.y;
        float br = v1.x, bi = v1.y;
        float cr = v2.x, ci = v2.y;
        float dr = v3.x, di = v3.y;
        float t0r = ar + cr, t0i = ai + ci;
        float t1r = ar - cr, t1i = ai - ci;
        float t2r = br + dr, t2i = bi + di;
        float t3r = br - dr, t3i = bi - di;
        re[i0] = t0r + t2r; im[i0] = t0i + t2i;
        float u1r = t1r + t3i, u1i = t1i - t3r;
        re[i1] = u1r * w1.x - u1i * w1.y; im[i1] = u1r * w1.y + u1i * w1.x;
        float u2r = t0r - t2r, u2i = t0i - t2i;
        re[i2] = u2r * w2.x - u2i * w2.y; im[i2] = u2r * w2.y + u2i * w2.x;
        float u3r = t1r - t3i, u3i = t1i + t3r;
        re[i3] = u3r * w3.x - u3i * w3.y; im[i3] = u3r * w3.y + u3i * w3.x;
    }
    __syncthreads();
    // ---- stages 1..4 through LDS ----
    #pragma unroll
    for (int s = 1; s < 5; ++s) {
        int log2Q = 8 - 2 * s;
        int Q = 1 << log2Q;
        int k = tid & (Q - 1);
        int g = tid >> log2Q;
        int base = (g << (log2Q + 2)) + k;
        int i0 = PADIX(base), i1 = PADIX(base + Q), i2 = PADIX(base + 2 * Q), i3 = PADIX(base + 3 * Q);
        int step = 2 << (2 * s);
        float2 w1 = twl[k * step];
        float2 w2 = twl[2 * k * step];
        float2 w3 = twl[3 * k * step];
        float ar = re[i0], ai = im[i0];
        float br = re[i1], bi = im[i1];
        float cr = re[i2], ci = im[i2];
        float dr = re[i3], di = im[i3];
        float t0r = ar + cr, t0i = ai + ci;
        float t1r = ar - cr, t1i = ai - ci;
        float t2r = br + dr, t2i = bi + di;
        float t3r = br - dr, t3i = bi - di;
        re[i0] = t0r + t2r; im[i0] = t0i + t2i;
        float u1r = t1r + t3i, u1i = t1i - t3r;
        re[i1] = u1r * w1.x - u1i * w1.y; im[i1] = u1r * w1.y + u1i * w1.x;
        float u2r = t0r - t2r, u2i = t0i - t2i;
        re[i2] = u2r * w2.x - u2i * w2.y; im[i2] = u2r * w2.y + u2i * w2.x;
        float u3r = t1r - t3i, u3i = t1i + t3r;
        re[i3] = u3r * w3.x - u3i * w3.y; im[i3] = u3r * w3.y + u3i * w3.x;
        __syncthreads();
    }
    // split: X[k] = E_k + e^{-2pi i k/2048} O_k (Z positions radix-4-digit-reversed)
    u16* xrow = XS + (size_t)row * XROW;
    if (tid < 31) {   // zero the band pad cells (341..351 | 693..703 | 1047..1055)
        int pp = (tid < 11) ? (341 + tid) : ((tid < 22) ? (682 + tid) : (1025 + tid));
        xrow[pp] = 0; xrow[1056 + pp] = 0; xrow[2112 + pp] = 0;
    }
    for (int k = tid; k <= 1024; k += 256) {
        float Xr, Xi;
        if (k == 0)        { Xr = re[0] + im[0]; Xi = 0.0f; }
        else if (k == 1024){ Xr = re[0] - im[0]; Xi = 0.0f; }
        else {
            int rv  = PADIX(rev4_10((unsigned)k));
            int rv2 = PADIX(rev4_10((unsigned)(1024 - k)));
            float2 t = twl[k];
            float Zr = re[rv],  Zi = im[rv];
            float Wr = re[rv2], Wi = im[rv2];
            float Er = 0.5f * (Zr + Wr), Ei = 0.5f * (Zi - Wi);
            float Or = 0.5f * (Zi + Wi), Oi = -0.5f * (Zr - Wr);
            Xr = Er + t.x * Or - t.y * Oi;
            Xi = Ei + t.x * Oi + t.y * Or;
        }
        float v = sqrtf(Xr * Xr + Xi * Xi);
        int zb = (k < S0c) ? 0 : ((k < S0c + S1c) ? 1 : 2);
        int pos = k + 11 * zb;   // z*352 + (k - O): band offsets 0/341/682 -> +0/+11/+22
        u16 h1, h2, h3;
        split3(v, h1, h2, h3);
        xrow[pos] = h1;
        xrow[1056 + pos] = h2;
        xrow[2112 + pos] = h3;
    }
}

// ---------------- K3: fused 3-band GEMM via pre-split bf16 planes ----------------
// r8 geometry (proven): wave tile 32x16, block 64x32, grid (32,11,3)=1056 (~4.1/CU).
// Y stored f32 (f64 accumulate, cast at store). Session ladder: 162.5 -> 134.0.
// Negative results, do not retry: r1/r2 ILP-via-VGPR (-23%), r5 LDS dbuf (neutral),
// r11 dist-fusion with in-loop split (+2), r12 epilogue-scatter + 32-block dist (+10),
// r15 last-block-done decide fusion (+52, cross-XCD fence stalls).
__global__ __launch_bounds__(256) void k_gemm(const u16* __restrict__ XS,
                                              const u16* __restrict__ AS,
                                              float* __restrict__ Y) {
    const int Sarr[3] = {S0c, S1c, S2c};
    const int Oarr[3] = {0, S0c, S0c + S1c};
    int z = blockIdx.z;
    int S = Sarr[z], O = Oarr[z];

    __shared__ u16 sX1[64][40], sX2[64][40], sX3[64][40];   // X rows (stride 40: b128-aligned)
    __shared__ u16 sA1[32][40], sA2[32][40], sA3[32][40];   // A cols(d)

    int r0 = blockIdx.x * 64;
    int d0 = blockIdx.y * 32;
    int tid = threadIdx.x;
    int lane = tid & 63, w = tid >> 6;
    int wm = (w >> 1) * 32, wn = (w & 1) * 16;   // wave tile: rows [wm,wm+32), cols [wn,wn+16)
    int fm = lane & 15, kq = lane >> 4;
    int row8 = tid >> 3, seg4 = (tid & 7) * 4;   // staging: 1 row x 4 contiguous k / thread

    // ---- runtime C/D layout calibration via the bf16 MFMA itself ----
    f32x4 z4 = {0.0f, 0.0f, 0.0f, 0.0f};
    short8 aone, afm;
    {
        u16 hone = 0x3F80;                 // bf16(1.0)
        u16 hfm = rneb((float)fm);         // exact for 0..15
        #pragma unroll
        for (int j = 0; j < 8; ++j) { aone[j] = (short)hone; afm[j] = (short)hfm; }
    }
    f32x4 calR = __builtin_amdgcn_mfma_f32_16x16x32_bf16(afm, aone, z4, 0, 0, 0);  // 32*row
    f32x4 calC = __builtin_amdgcn_mfma_f32_16x16x32_bf16(aone, afm, z4, 0, 0, 0);  // 32*col
    int rIdx[4], cIdx[4];
    #pragma unroll
    for (int i = 0; i < 4; ++i) {
        rIdx[i] = (int)(calR[i] * 0.03125f + 0.5f);
        cIdx[i] = (int)(calC[i] * 0.03125f + 0.5f);
    }

    // staging sources: X rows row8 and row8+32; A col-row row8 (all u16x4 8B-aligned)
    const u16* xb0 = XS + (size_t)(r0 + row8) * XROW + (size_t)z * KPAD + seg4;
    const u16* xb1 = xb0 + 32 * (size_t)XROW;
    const u16* ab  = AS + ((size_t)z * KPAD + (d0 + row8)) * KPAD + seg4;

    u16x4 wxa1, wxa2, wxa3, wxb1, wxb2, wxb3, wa1, wa2, wa3;
    auto load_tile = [&](int st) {
        int ko = st * 32;
        wxa1 = *(const u16x4*)(xb0 + ko);
        wxa2 = *(const u16x4*)(xb0 + 1056 + ko);
        wxa3 = *(const u16x4*)(xb0 + 2112 + ko);
        wxb1 = *(const u16x4*)(xb1 + ko);
        wxb2 = *(const u16x4*)(xb1 + 1056 + ko);
        wxb3 = *(const u16x4*)(xb1 + 2112 + ko);
        wa1  = *(const u16x4*)(ab + ko);
        wa2  = *(const u16x4*)(ab + APLANE + ko);
        wa3  = *(const u16x4*)(ab + 2 * (size_t)APLANE + ko);
    };

    double acc0[4] = {0.0, 0.0, 0.0, 0.0};
    double acc1[4] = {0.0, 0.0, 0.0, 0.0};
    load_tile(0);
    const int nsteps = KPAD / 32;   // 11, uniform across bands
    for (int st = 0; st < nsteps; ++st) {
        __syncthreads();
        *(u16x4*)&sX1[row8][seg4] = wxa1;
        *(u16x4*)&sX2[row8][seg4] = wxa2;
        *(u16x4*)&sX3[row8][seg4] = wxa3;
        *(u16x4*)&sX1[row8 + 32][seg4] = wxb1;
        *(u16x4*)&sX2[row8 + 32][seg4] = wxb2;
        *(u16x4*)&sX3[row8 + 32][seg4] = wxb3;
        *(u16x4*)&sA1[row8][seg4] = wa1;
        *(u16x4*)&sA2[row8][seg4] = wa2;
        *(u16x4*)&sA3[row8][seg4] = wa3;
        __syncthreads();
        if (st + 1 < nsteps) load_tile(st + 1);
        short8 b1 = *(const short8*)&sA1[wn + fm][kq * 8];
        short8 b2 = *(const short8*)&sA2[wn + fm][kq * 8];
        short8 b3 = *(const short8*)&sA3[wn + fm][kq * 8];
        {   // row-subtile 0: rows wm..wm+15
            short8 a1 = *(const short8*)&sX1[wm + fm][kq * 8];
            short8 a2 = *(const short8*)&sX2[wm + fm][kq * 8];
            short8 a3 = *(const short8*)&sX3[wm + fm][kq * 8];
            f32x4 p1 = __builtin_amdgcn_mfma_f32_16x16x32_bf16(a1, b1, z4, 0, 0, 0);
            f32x4 p2 = __builtin_amdgcn_mfma_f32_16x16x32_bf16(a1, b2, z4, 0, 0, 0);
            p2 = __builtin_amdgcn_mfma_f32_16x16x32_bf16(a2, b1, p2, 0, 0, 0);
            p2 = __builtin_amdgcn_mfma_f32_16x16x32_bf16(a1, b3, p2, 0, 0, 0);
            p2 = __builtin_amdgcn_mfma_f32_16x16x32_bf16(a2, b2, p2, 0, 0, 0);
            p2 = __builtin_amdgcn_mfma_f32_16x16x32_bf16(a3, b1, p2, 0, 0, 0);
            #pragma unroll
            for (int i = 0; i < 4; ++i) acc0[i] += (double)p1[i] + (double)p2[i];
        }
        {   // row-subtile 1: rows wm+16..wm+31
            short8 a1 = *(const short8*)&sX1[wm + 16 + fm][kq * 8];
            short8 a2 = *(const short8*)&sX2[wm + 16 + fm][kq * 8];
            short8 a3 = *(const short8*)&sX3[wm + 16 + fm][kq * 8];
            f32x4 p1 = __builtin_amdgcn_mfma_f32_16x16x32_bf16(a1, b1, z4, 0, 0, 0);
            f32x4 p2 = __builtin_amdgcn_mfma_f32_16x16x32_bf16(a1, b2, z4, 0, 0, 0);
            p2 = __builtin_amdgcn_mfma_f32_16x16x32_bf16(a2, b1, p2, 0, 0, 0);
            p2 = __builtin_amdgcn_mfma_f32_16x16x32_bf16(a1, b3, p2, 0, 0, 0);
            p2 = __builtin_amdgcn_mfma_f32_16x16x32_bf16(a2, b2, p2, 0, 0, 0);
            p2 = __builtin_amdgcn_mfma_f32_16x16x32_bf16(a3, b1, p2, 0, 0, 0);
            #pragma unroll
            for (int i = 0; i < 4; ++i) acc1[i] += (double)p1[i] + (double)p2[i];
        }
    }
    #pragma unroll
    for (int i = 0; i < 4; ++i) {
        int d = d0 + wn + cIdx[i];
        if (d < S) {
            Y[(size_t)(r0 + wm + rIdx[i]) * NFREQ + O + d] = (float)acc0[i];
            Y[(size_t)(r0 + wm + 16 + rIdx[i]) * NFREQ + O + d] = (float)acc1[i];
        }
    }
}

// ---------------- K4: weighted Gram partials via f64 MFMA, G = Yw Yw^T ----------------
// grid (32 batches, 8 dim-chunks); block 256 = 4 waves (2x2 quadrants of the 64x64 G).
// Y is f32 (upcast at load; f64 accumulation & LDS unchanged).
__global__ __launch_bounds__(256) void k_dist(const float* __restrict__ Y,
                                              const float* __restrict__ fw,
                                              double* __restrict__ part) {
    __shared__ double sY[64][34];   // [row][k] f64
    int b = blockIdx.x;
    int chunk = blockIdx.y;
    int dlo = chunk * 128;
    int dhi = (chunk == 7) ? NFREQ : dlo + 128;
    int tid = threadIdx.x;
    int lane = tid & 63, w = tid >> 6;
    int wm = (w >> 1) * 32, wn = (w & 1) * 32;
    int fm = lane & 15, kq = lane >> 4;
    int kl = tid & 31, rl = tid >> 5;

    double f0 = (double)fw[0], f1 = (double)fw[1], f2 = (double)fw[2];
    double m = fmax(f0, fmax(f1, f2));
    double e0 = exp(f0 - m), e1 = exp(f1 - m), e2 = exp(f2 - m);
    double esum = e0 + e1 + e2;
    double sw0 = sqrt(e0 / esum), sw1 = sqrt(e1 / esum), sw2 = sqrt(e2 / esum);

    v4d zero = {0.0, 0.0, 0.0, 0.0};
    double aval = (double)fm;
    v4d calR = __builtin_amdgcn_mfma_f64_16x16x4f64(aval, 1.0, zero, 0, 0, 0);
    v4d calC = __builtin_amdgcn_mfma_f64_16x16x4f64(1.0, aval, zero, 0, 0, 0);
    int rIdx[4], cIdx[4];
    #pragma unroll
    for (int i = 0; i < 4; ++i) {
        rIdx[i] = (int)(calR[i] * 0.25);
        cIdx[i] = (int)(calC[i] * 0.25);
    }

    const float* Yb = Y + (size_t)b * Cn * NFREQ;
    auto load_tile = [&](int k0, double* py) {
        int d = dlo + k0 + kl;
        bool dv = d < dhi;
        double sw = dv ? ((d < S0c) ? sw0 : ((d < S0c + S1c) ? sw1 : sw2)) : 0.0;
        #pragma unroll
        for (int i = 0; i < 8; ++i)
            py[i] = dv ? (double)Yb[(size_t)(rl + 8 * i) * NFREQ + d] * sw : 0.0;
    };

    v4d acc00 = zero, acc01 = zero, acc10 = zero, acc11 = zero;
    double py[8];
    load_tile(0, py);
    int nsteps = (dhi - dlo + 31) / 32;
    for (int st = 0; st < nsteps; ++st) {
        __syncthreads();
        #pragma unroll
        for (int i = 0; i < 8; ++i) sY[rl + 8 * i][kl] = py[i];
        __syncthreads();
        if (st + 1 < nsteps) load_tile((st + 1) * 32, py);
        #pragma unroll
        for (int t = 0; t < 8; ++t) {
            int k = 4 * t + kq;
            double a0 = sY[wm + fm][k];
            double a1 = sY[wm + 16 + fm][k];
            double b0 = sY[wn + fm][k];
            double b1 = sY[wn + 16 + fm][k];
            acc00 = __builtin_amdgcn_mfma_f64_16x16x4f64(a0, b0, acc00, 0, 0, 0);
            acc01 = __builtin_amdgcn_mfma_f64_16x16x4f64(a0, b1, acc01, 0, 0, 0);
            acc10 = __builtin_amdgcn_mfma_f64_16x16x4f64(a1, b0, acc10, 0, 0, 0);
            acc11 = __builtin_amdgcn_mfma_f64_16x16x4f64(a1, b1, acc11, 0, 0, 0);
        }
    }
    double* pb = part + (((size_t)b * 8 + chunk) << 12);
    #pragma unroll
    for (int i = 0; i < 4; ++i) {
        int rowA = wm + rIdx[i], rowB = rowA + 16;
        int cA = wn + cIdx[i], cB = cA + 16;
        pb[rowA * 64 + cA] = acc00[i];
        pb[rowA * 64 + cB] = acc01[i];
        pb[rowB * 64 + cA] = acc10[i];
        pb[rowB * 64 + cB] = acc11[i];
    }
}

// ---------------- K5: sum Gram partials, dist = Gii+Gjj-2Gij, gumbel decision ----------------
// grid (32 batches, 16 row-groups); block 256 = 4 waves, one wave per matrix row.
__global__ __launch_bounds__(256) void k_decide(const double* __restrict__ part,
                                                const float* __restrict__ gum,
                                                float* __restrict__ out) {
    __shared__ double sQ[64];
    int b = blockIdx.x;
    int tid = threadIdx.x;
    const double* pb = part + (((size_t)b * 8) << 12);
    if (tid < 64) {
        double q = 0.0;
        #pragma unroll
        for (int c = 0; c < 8; ++c) q += pb[((size_t)c << 12) + tid * 65];
        sQ[tid] = q;
    }
    __syncthreads();
    int i = blockIdx.y * 4 + (tid >> 6);
    int j = tid & 63;
    double g = 0.0;
    #pragma unroll
    for (int c = 0; c < 8; ++c) g += pb[((size_t)c << 12) + i * 64 + j];
    double dist = fmax(sQ[i] + sQ[j] - 2.0 * g, 0.0);
    double e = (i == j) ? 0.0 : 1.0 / (dist + 1e-10);
    double emax = e;
    #pragma unroll
    for (int off = 32; off; off >>= 1)
        emax = fmax(emax, __shfl_xor(emax, off, 64));
    double p = (i == j) ? 0.99 : (e / emax) * 0.99;
    double l0 = log(p / (1.0 - p));
    double l1 = -l0;   // log((1-p)/p) == -log(p/(1-p)) exactly; margins are >> 1 ulp
    int idx = i * 64 + j;
    const float* gb = gum + (size_t)b * 8192;
    double y0 = l0 + (double)gb[2 * idx];
    double y1 = l1 + (double)gb[2 * idx + 1];
    out[(size_t)b * 4096 + idx] = (y0 >= y1) ? 1.0f : 0.0f;  // ST == one-hot exactly
}

// ---------------- launcher ----------------
extern "C" void kernel_launch(void* const* d_in, const int* in_sizes, int n_in,
                              void* d_out, int out_size, void* d_ws, size_t ws_size,
                              hipStream_t stream) {
    const float* X  = (const float*)d_in[0];
    const float* A0 = (const float*)d_in[1];
    const float* A1 = (const float*)d_in[2];
    const float* A2 = (const float*)d_in[3];
    const float* fw = (const float*)d_in[4];
    const float* gm = (const float*)d_in[5];
    float* out = (float*)d_out;

    char* ws = (char*)d_ws;
    u16*  XS = (u16*)(ws + 32768);                 // 2048*3168*2 = 12,976,128 B -> ends 13,008,896
    u16*  AS = (u16*)(ws + 13008896);              // 3*371712*2  =  2,230,272 B -> ends 15,239,168
    float* Y = (float*)(ws + 15239168);            // 2048*1025*4 = 8,396,800 B -> ends 23,635,968
    // part aliases XS (dead after gemm): 32*8*4096*8 = 8,388,608 B <= 12,976,128 B
    double* part = (double*)(ws + 32768);

    k_fftprep<<<Bn * Cn + 1452, 256, 0, stream>>>(X, A0, A1, A2, XS, AS);
    k_gemm<<<dim3(32, 11, 3), 256, 0, stream>>>(XS, AS, Y);
    k_dist<<<dim3(Bn, 8), 256, 0, stream>>>(Y, fw, part);
    k_decide<<<dim3(Bn, 16), 256, 0, stream>>>(part, gm, out);
}